// Round 1
// baseline (22.359 us; speedup 1.0000x reference)
//
#include <hip/hip_runtime.h>
#include <hip/hip_bf16.h>

// out[row, :] = projection[idx[row], :]
// row count = B*T = 16384, row width = N_EMBD = 1024 floats = 4 KiB.
// One 256-thread block per row; each lane moves one float4 (16 B).
__global__ void IdentityEmbedding_14147622273767_kernel(
    const int* __restrict__ idx,
    const float* __restrict__ proj,
    float* __restrict__ out) {
    const int row = blockIdx.x;          // 0 .. 16383
    const int t   = threadIdx.x;         // 0 .. 255
    const size_t src_row = (size_t)idx[row] * 1024;  // block-uniform -> scalar load
    const size_t dst_row = (size_t)row * 1024;
    const float4* __restrict__ src = reinterpret_cast<const float4*>(proj + src_row);
    float4* __restrict__ dst       = reinterpret_cast<float4*>(out + dst_row);
    dst[t] = src[t];
}

extern "C" void kernel_launch(void* const* d_in, const int* in_sizes, int n_in,
                              void* d_out, int out_size, void* d_ws, size_t ws_size,
                              hipStream_t stream) {
    const int*   idx  = (const int*)d_in[0];     // (B*T,) int
    const float* proj = (const float*)d_in[1];   // (VOCAB, N_EMBD) f32
    float*       out  = (float*)d_out;           // (B*T, N_EMBD) f32
    const int nrows = in_sizes[0];               // 16384
    IdentityEmbedding_14147622273767_kernel<<<nrows, 256, 0, stream>>>(idx, proj, out);
}

// Round 2
// 16.268 us; speedup vs baseline: 1.3744x; 1.3744x over previous
//
#include <hip/hip_runtime.h>
#include <hip/hip_bf16.h>

// IdentityEmbedding: projection is the constant [I_1024; 0] (built in
// __init__, not data), so gather(projection, idx) == one-hot comparator:
//   out[row, j] = (idx[row] == j && idx[row] < 1024) ? 1.0f : 0.0f
// This removes the 64 MiB projection fetch entirely; the kernel is a pure
// 64 MiB streaming write (+ 64 KiB idx read).
//
// One 256-thread block per row (1024 f32 = 256 float4). Lane t owns
// elements [4t, 4t+4). The unique lane with (idx>>2)==t (only possible
// when idx < 1024) sets one component to 1.0.

typedef float f32x4 __attribute__((ext_vector_type(4)));

__global__ void IdentityEmbedding_14147622273767_kernel(
    const int* __restrict__ idx,
    float* __restrict__ out) {
    const int row = blockIdx.x;          // 0 .. 16383
    const int t   = threadIdx.x;         // 0 .. 255
    const int iv  = idx[row];            // block-uniform -> scalar load

    f32x4 v = {0.0f, 0.0f, 0.0f, 0.0f};
    if ((iv >> 2) == t) {                // t < 256 => implies iv < 1024
        v[iv & 3] = 1.0f;
    }

    f32x4* __restrict__ dst =
        reinterpret_cast<f32x4*>(out + (size_t)row * 1024);
    __builtin_nontemporal_store(v, dst + t);
}

extern "C" void kernel_launch(void* const* d_in, const int* in_sizes, int n_in,
                              void* d_out, int out_size, void* d_ws, size_t ws_size,
                              hipStream_t stream) {
    const int* idx = (const int*)d_in[0];   // (B*T,) int32
    float*     out = (float*)d_out;         // (B*T, N_EMBD) f32
    const int nrows = in_sizes[0];          // 16384
    IdentityEmbedding_14147622273767_kernel<<<nrows, 256, 0, stream>>>(idx, out);
}